// Round 3
// baseline (9746.320 us; speedup 1.0000x reference)
//
#include <hip/hip_runtime.h>
#include <stdint.h>
#include <math.h>

#define T 4096
#define NTAGS 6
#define START_TAG 3
#define STOP_TAG 4
#define NEGV -10000.0f

__device__ __forceinline__ float sigm_fast(float z) {
  return 1.f / (1.f + __expf(-z));
}
__device__ __forceinline__ float tanh_fast(float z) {
  return 1.f - 2.f / (1.f + __expf(2.f * z));   // exact at +/-inf saturation
}

// ---------------------------------------------------------------------------
// K0: transpose w_ih (both dirs) into wT[k][col], col = d*1024+g; combined bias
// ---------------------------------------------------------------------------
__global__ __launch_bounds__(256) void k0_prep(
    const float* __restrict__ wf, const float* __restrict__ wb,
    const float* __restrict__ bif, const float* __restrict__ bhf,
    const float* __restrict__ bib, const float* __restrict__ bhb,
    float* __restrict__ wT, float* __restrict__ bias2) {
  int idx = blockIdx.x * 256 + threadIdx.x;   // 0 .. 524287
  int k = idx >> 11, col = idx & 2047;
  int d = col >> 10, g = col & 1023;
  const float* w = d ? wb : wf;
  wT[idx] = w[g * 256 + k];                   // wT[k*2048 + col]
  if (idx < 2048) bias2[idx] = d ? (bib[g] + bhb[g]) : (bif[g] + bhf[g]);
}

// ---------------------------------------------------------------------------
// K1: zpre[d][t][g] = emb[sent[t]] . w_ih[d][g] + b_ih + b_hh
// ---------------------------------------------------------------------------
__global__ __launch_bounds__(256) void k1_zpre(
    const int* __restrict__ sent, const float* __restrict__ emb,
    const float* __restrict__ wT, const float* __restrict__ bias2,
    float* __restrict__ zpre) {
  int tb = blockIdx.x, cb = blockIdx.y;
  int tid = threadIdx.x;
  int col = cb * 256 + tid;
  int d = col >> 10, g = col & 1023;
  __shared__ float xs[32 * 256];
  int t0 = tb * 32;
  for (int r = 0; r < 32; r++) {
    int s = sent[t0 + r];                       // uniform -> scalar broadcast
    xs[r * 256 + tid] = emb[(size_t)s * 256 + tid];
  }
  __syncthreads();
  float acc[32];
#pragma unroll
  for (int r = 0; r < 32; r++) acc[r] = 0.f;
  const float4* xs4 = (const float4*)xs;
  for (int kq = 0; kq < 64; kq++) {
    float w0 = wT[(4 * kq + 0) * 2048 + col];
    float w1 = wT[(4 * kq + 1) * 2048 + col];
    float w2 = wT[(4 * kq + 2) * 2048 + col];
    float w3 = wT[(4 * kq + 3) * 2048 + col];
#pragma unroll
    for (int r = 0; r < 32; r++) {
      float4 x4 = xs4[r * 64 + kq];             // uniform address -> broadcast
      acc[r] += w0 * x4.x + w1 * x4.y + w2 * x4.z + w3 * x4.w;
    }
  }
  float bb = bias2[col];
  for (int r = 0; r < 32; r++)
    zpre[((size_t)d * T + (t0 + r)) * 1024 + g] = acc[r] + bb;
}

// ---------------------------------------------------------------------------
// K2: sequential BiLSTM recurrence. 8 WGs (= d*4+wg), 512 thr each.
// WG owns cells [64wg,64wg+64) -> 256 gate rows; 2 threads/row, 128 fp32
// weights/thread. Weight residency is FORCED via an opaque asm pin after the
// one-time load: the defs become inline-asm results, which the compiler can
// neither rematerialize as loads nor sink into the loop. launch_bounds(512,2)
// -> 256-VGPR cap, ~190 needed, so no spill either. (Rounds 1-2 showed
// VGPR=52/80: the compiler was re-streaming 256KB/step/WG from L2 = the
// observed 4100 cyc/step wall.)
// Cross-WG h exchange: 2-slot ring of {step_tag,h_bits} packed 8B atomic
// stores at AGENT scope (MALL); consumers poll the tagged data directly.
// zpre for step s+1 is prefetched before the step-s poll (latency hidden).
// ---------------------------------------------------------------------------
__global__ __launch_bounds__(512, 2) void k2_lstm(
    const float* __restrict__ zpre,
    const float* __restrict__ whf, const float* __restrict__ whb,
    const float* __restrict__ h0, const float* __restrict__ c0,
    float* h_all, unsigned long long* ring) {
  int bx = blockIdx.x;
  int d = bx >> 2, wg = bx & 3;
  const float* w_hh = d ? whb : whf;
  int tid = threadIdx.x;
  int row = tid >> 1, q = tid & 1;            // 2 lanes per gate row
  int gate = row >> 6, cl = row & 63;         // 0=i,1=f,2=g,3=o
  int B = wg * 64;
  int g_row = gate * 256 + B + cl;

  float4 w4[32];                              // 128 weights, k in [128q,128q+128)
  {
    const float4* wp = (const float4*)(w_hh + (size_t)g_row * 256 + q * 128);
#pragma unroll
    for (int m = 0; m < 32; m++) w4[m] = wp[m];
  }
  // Opaque pin: values now defined by asm, not by loads -> must stay in VGPRs.
#pragma unroll
  for (int m = 0; m < 32; m++)
    asm volatile("" : "+v"(w4[m].x), "+v"(w4[m].y), "+v"(w4[m].z), "+v"(w4[m].w));

  // pitch-72 chunks by source WG: broadcast b128 reads, conflict-free
  __shared__ float h_pad[4 * 72];
  __shared__ float z_lds[256];
  float c = 0.f;
  if (tid < 64) c = c0[d * 256 + B + tid];
  const float* zp_d = zpre + (size_t)d * T * 1024;
  float* h_d = h_all + (size_t)d * T * 256;
  unsigned long long* rg = ring + (size_t)d * 2 * 256;

  int chunk = tid >> 6;                        // valid for tid<256
  bool is_poll = (tid < 256) && (chunk != wg); // own chunk filled by producer
  size_t zoff = (size_t)gate * 256 + B + cl;   // this thread's z element

  // prologue: z for s=0
  float zv = 0.f;
  {
    int t0 = d ? (T - 1) : 0;
    if (q == 0) zv = zp_d[(size_t)t0 * 1024 + zoff];
  }

  for (int s = 0; s < T; s++) {
    int t = d ? (T - 1 - s) : s;
    // prefetch z for step s+1 BEFORE the poll -> latency hidden under spin
    float zv_next = 0.f;
    if (q == 0 && s + 1 < T) {
      int tn = d ? (t - 1) : (t + 1);
      zv_next = zp_d[(size_t)tn * 1024 + zoff];
    }

    if (s == 0) {
      if (tid < 256) h_pad[chunk * 72 + (tid & 63)] = h0[d * 256 + tid];
    } else if (is_poll) {
      unsigned exp_tag = (unsigned)(s - 1);
      unsigned long long* addr = &rg[((s - 1) & 1) * 256 + tid];
      unsigned long long v;
      do {
        v = __hip_atomic_load(addr, __ATOMIC_RELAXED, __HIP_MEMORY_SCOPE_AGENT);
      } while ((unsigned)(v >> 32) != exp_tag);
      union { unsigned u; float f; } cv; cv.u = (unsigned)v;
      h_pad[chunk * 72 + (tid & 63)] = cv.f;
    }
    __syncthreads();                           // A: h_pad complete

    const float4* hp0 = (const float4*)(h_pad + (2 * q) * 72);
    const float4* hp1 = (const float4*)(h_pad + (2 * q + 1) * 72);
    float acc = 0.f;
#pragma unroll
    for (int m = 0; m < 16; m++) {
      float4 h4 = hp0[m];
      acc += w4[m].x * h4.x + w4[m].y * h4.y + w4[m].z * h4.z + w4[m].w * h4.w;
    }
#pragma unroll
    for (int m = 0; m < 16; m++) {
      float4 h4 = hp1[m];
      acc += w4[16 + m].x * h4.x + w4[16 + m].y * h4.y
           + w4[16 + m].z * h4.z + w4[16 + m].w * h4.w;
    }
    acc += __shfl_xor(acc, 1);
    if (q == 0) {
      float z = acc + zv;
      z_lds[row] = (gate == 2) ? tanh_fast(z) : sigm_fast(z);
    }
    __syncthreads();                           // B: activations complete

    if (tid < 64) {
      float iA = z_lds[tid], fA = z_lds[64 + tid];
      float gA = z_lds[128 + tid], oA = z_lds[192 + tid];
      c = fA * c + iA * gA;
      float hv = oA * tanh_fast(c);
      union { float f; unsigned u; } cv; cv.f = hv;
      // critical store first: tagged push to MALL for the other 3 WGs
      __hip_atomic_store(&rg[(s & 1) * 256 + B + tid],
                         ((unsigned long long)(unsigned)s << 32) | cv.u,
                         __ATOMIC_RELAXED, __HIP_MEMORY_SCOPE_AGENT);
      h_pad[wg * 72 + tid] = hv;               // self chunk for next step
      h_d[(size_t)t * 256 + B + tid] = hv;     // plain history for k3
    }
    zv = zv_next;
  }
}

// ---------------------------------------------------------------------------
// K3: feats[t][tag] = [hf[t]; hb[t]] . W_out[tag] + b_out[tag]
// ---------------------------------------------------------------------------
__global__ __launch_bounds__(64) void k3_feats(
    const float* __restrict__ h_all, const float* __restrict__ Wout,
    const float* __restrict__ bout, float* __restrict__ feats) {
  int t = blockIdx.x;
  int j = threadIdx.x;
  const float* hf = h_all + (size_t)t * 256;
  const float* hb = h_all + (size_t)T * 256 + (size_t)t * 256;
  float s[6];
#pragma unroll
  for (int g = 0; g < 6; g++) s[g] = 0.f;
#pragma unroll
  for (int m = 0; m < 4; m++) {
    float a = hf[j + 64 * m];
#pragma unroll
    for (int g = 0; g < 6; g++) s[g] += a * Wout[g * 512 + j + 64 * m];
  }
#pragma unroll
  for (int m = 0; m < 4; m++) {
    float b = hb[j + 64 * m];
#pragma unroll
    for (int g = 0; g < 6; g++) s[g] += b * Wout[g * 512 + 256 + j + 64 * m];
  }
#pragma unroll
  for (int g = 0; g < 6; g++) {
#pragma unroll
    for (int off = 32; off >= 1; off >>= 1) s[g] += __shfl_xor(s[g], off);
  }
  if (j < 6) feats[(size_t)t * 6 + j] = s[j] + bout[j];
}

// ---------------------------------------------------------------------------
// K4: Viterbi forward (serial, first-max argmax like jnp.argmax) + parallel
// backtrace via 6-entry map-composition suffix scan. Single wave.
// ---------------------------------------------------------------------------
__global__ __launch_bounds__(64) void k4_viterbi(
    const float* __restrict__ feats, const float* __restrict__ trans,
    float* __restrict__ out) {
  __shared__ unsigned char bp_lds[T * 8];
  __shared__ float fbuf[2][64 * 6];
  int lane = threadIdx.x;

  float tr[6];
#pragma unroll
  for (int f = 0; f < 6; f++) tr[f] = (lane < 6) ? trans[lane * 6 + f] : 0.f;
  float fv = (lane == START_TAG) ? 0.f : NEGV;

  for (int idx = lane; idx < 384; idx += 64) fbuf[0][idx] = feats[idx];

  for (int cch = 0; cch < 64; cch++) {
    float pf[6];
    if (cch + 1 < 64) {
#pragma unroll
      for (int m = 0; m < 6; m++)
        pf[m] = feats[(cch + 1) * 384 + lane + 64 * m];   // prefetch in regs
    }
    const float* fb = fbuf[cch & 1];
    for (int j = 0; j < 64; j++) {
      int t = cch * 64 + j;
      float best = -3.4e38f;
      int bi = 0;
#pragma unroll
      for (int f = 0; f < 6; f++) {
        float v = __shfl(fv, f) + tr[f];     // trans[to][from] + fv[from]
        if (v > best) { best = v; bi = f; }  // strict > => first max index
      }
      float nfv = best + fb[j * 6 + (lane < 6 ? lane : 0)];
      if (lane < 6) {
        fv = nfv;
        bp_lds[t * 8 + lane] = (unsigned char)bi;
      }
    }
    if (cch + 1 < 64) {
#pragma unroll
      for (int m = 0; m < 6; m++)
        fbuf[(cch + 1) & 1][lane + 64 * m] = pf[m];
    }
  }

  float term = (lane < 6) ? (fv + trans[STOP_TAG * 6 + lane]) : -3.4e38f;
  float bestv = -3.4e38f;
  int bestt = 0;
#pragma unroll
  for (int f = 0; f < 6; f++) {
    float v = __shfl(term, f);
    if (v > bestv) { bestv = v; bestt = f; }
  }
  if (lane == 0) out[0] = bestv;

  // backtrace: path[t] = S_t(best), S_t = M_{t+1} o ... o M_{T-1}
  unsigned int ident = 0;
#pragma unroll
  for (int i = 0; i < 6; i++) ident |= (unsigned)i << (3 * i);

  unsigned int p = ident;                 // P_L = M_{64L} o ... o M_{64L+63}
  int base = lane * 64;
  for (int j2 = 0; j2 < 64; j2++) {
    const unsigned int* bw = (const unsigned int*)&bp_lds[(base + j2) * 8];
    unsigned int lo = bw[0], hi = bw[1];
    unsigned int mw = (lo & 7) | (((lo >> 8) & 7) << 3) | (((lo >> 16) & 7) << 6)
                    | (((lo >> 24) & 7) << 9) | ((hi & 7) << 12)
                    | (((hi >> 8) & 7) << 15);
    unsigned int np = 0;
#pragma unroll
    for (int i = 0; i < 6; i++) {
      unsigned int b = (mw >> (3 * i)) & 7;
      np |= ((p >> (3 * b)) & 7) << (3 * i);   // p := p o M_t
    }
    p = np;
  }
  unsigned int suf = p;   // suffix scan: suf_L = P_L o ... o P_63
#pragma unroll
  for (int off = 1; off < 64; off <<= 1) {
    unsigned int other = __shfl_down(suf, off);
    if (lane + off < 64) {
      unsigned int ns = 0;
#pragma unroll
      for (int i = 0; i < 6; i++) {
        unsigned int b = (other >> (3 * i)) & 7;
        ns |= ((suf >> (3 * b)) & 7) << (3 * i);   // suf := suf o other
      }
      suf = ns;
    }
  }
  unsigned int tail = __shfl_down(suf, 1);     // Suf_{L+1}
  if (lane == 63) tail = ident;
  unsigned int cur = tail;                     // = S_{64L+63}
  for (int j2 = 63; j2 >= 0; j2--) {
    int t = base + j2;
    out[1 + t] = (float)((cur >> (3 * bestt)) & 7);
    const unsigned int* bw = (const unsigned int*)&bp_lds[t * 8];
    unsigned int lo = bw[0], hi = bw[1];
    unsigned int mw = (lo & 7) | (((lo >> 8) & 7) << 3) | (((lo >> 16) & 7) << 6)
                    | (((lo >> 24) & 7) << 9) | ((hi & 7) << 12)
                    | (((hi >> 8) & 7) << 15);
    unsigned int nc = 0;
#pragma unroll
    for (int i = 0; i < 6; i++) {
      unsigned int b = (cur >> (3 * i)) & 7;
      nc |= ((mw >> (3 * b)) & 7) << (3 * i);  // cur := M_t o cur
    }
    cur = nc;
  }
}

// ---------------------------------------------------------------------------
extern "C" void kernel_launch(void* const* d_in, const int* in_sizes, int n_in,
                              void* d_out, int out_size, void* d_ws, size_t ws_size,
                              hipStream_t stream) {
  const int*   sent  = (const int*)d_in[0];
  const float* emb   = (const float*)d_in[1];
  const float* wihf  = (const float*)d_in[2];
  const float* whhf  = (const float*)d_in[3];
  const float* bihf  = (const float*)d_in[4];
  const float* bhhf  = (const float*)d_in[5];
  const float* wihb  = (const float*)d_in[6];
  const float* whhb  = (const float*)d_in[7];
  const float* bihb  = (const float*)d_in[8];
  const float* bhhb  = (const float*)d_in[9];
  const float* Wout  = (const float*)d_in[10];
  const float* bout  = (const float*)d_in[11];
  const float* trans = (const float*)d_in[12];
  const float* h0    = (const float*)d_in[13];
  const float* c0    = (const float*)d_in[14];
  float* out = (float*)d_out;

  char* ws = (char*)d_ws;
  float*              zpre  = (float*)(ws + 0);          // 32 MiB
  float*              h_all = (float*)(ws + 33554432);   //  8 MiB
  float*              wT    = (float*)(ws + 41943040);   //  2 MiB
  float*              bias2 = (float*)(ws + 44040192);   //  8 KiB
  float*              feats = (float*)(ws + 44048384);   // 96 KiB
  unsigned long long* ring  = (unsigned long long*)(ws + 44146688); // 8 KiB

  k0_prep<<<2048, 256, 0, stream>>>(wihf, wihb, bihf, bhhf, bihb, bhhb, wT, bias2);
  dim3 g1(128, 8);
  k1_zpre<<<g1, 256, 0, stream>>>(sent, emb, wT, bias2, zpre);
  k2_lstm<<<8, 512, 0, stream>>>(zpre, whhf, whhb, h0, c0, h_all, ring);
  k3_feats<<<4096, 64, 0, stream>>>(h_all, Wout, bout, feats);
  k4_viterbi<<<1, 64, 0, stream>>>(feats, trans, out);
}

// Round 4
// 6717.469 us; speedup vs baseline: 1.4509x; 1.4509x over previous
//
#include <hip/hip_runtime.h>
#include <stdint.h>
#include <math.h>

#define T 4096
#define NTAGS 6
#define START_TAG 3
#define STOP_TAG 4
#define NEGV -10000.0f

__device__ __forceinline__ float sigm_fast(float z) {
  return 1.f / (1.f + __expf(-z));
}
__device__ __forceinline__ float tanh_fast(float z) {
  return 1.f - 2.f / (1.f + __expf(2.f * z));   // exact at +/-inf saturation
}

typedef _Float16 half2v __attribute__((ext_vector_type(2)));
__device__ __forceinline__ float dot2acc(unsigned a, unsigned b, float c) {
  return __builtin_amdgcn_fdot2(__builtin_bit_cast(half2v, a),
                                __builtin_bit_cast(half2v, b), c, false);
}
__device__ __forceinline__ unsigned short f16b(float x) {
  _Float16 h = (_Float16)x;
  return __builtin_bit_cast(unsigned short, h);
}

// ---------------------------------------------------------------------------
// K0: transpose w_ih (both dirs) into wT[k][col], col = d*1024+g; combined bias
// ---------------------------------------------------------------------------
__global__ __launch_bounds__(256) void k0_prep(
    const float* __restrict__ wf, const float* __restrict__ wb,
    const float* __restrict__ bif, const float* __restrict__ bhf,
    const float* __restrict__ bib, const float* __restrict__ bhb,
    float* __restrict__ wT, float* __restrict__ bias2) {
  int idx = blockIdx.x * 256 + threadIdx.x;   // 0 .. 524287
  int k = idx >> 11, col = idx & 2047;
  int d = col >> 10, g = col & 1023;
  const float* w = d ? wb : wf;
  wT[idx] = w[g * 256 + k];                   // wT[k*2048 + col]
  if (idx < 2048) bias2[idx] = d ? (bib[g] + bhb[g]) : (bif[g] + bhf[g]);
}

// ---------------------------------------------------------------------------
// K1: zpre[d][t][g] = emb[sent[t]] . w_ih[d][g] + b_ih + b_hh
// ---------------------------------------------------------------------------
__global__ __launch_bounds__(256) void k1_zpre(
    const int* __restrict__ sent, const float* __restrict__ emb,
    const float* __restrict__ wT, const float* __restrict__ bias2,
    float* __restrict__ zpre) {
  int tb = blockIdx.x, cb = blockIdx.y;
  int tid = threadIdx.x;
  int col = cb * 256 + tid;
  int d = col >> 10, g = col & 1023;
  __shared__ float xs[32 * 256];
  int t0 = tb * 32;
  for (int r = 0; r < 32; r++) {
    int s = sent[t0 + r];                       // uniform -> scalar broadcast
    xs[r * 256 + tid] = emb[(size_t)s * 256 + tid];
  }
  __syncthreads();
  float acc[32];
#pragma unroll
  for (int r = 0; r < 32; r++) acc[r] = 0.f;
  const float4* xs4 = (const float4*)xs;
  for (int kq = 0; kq < 64; kq++) {
    float w0 = wT[(4 * kq + 0) * 2048 + col];
    float w1 = wT[(4 * kq + 1) * 2048 + col];
    float w2 = wT[(4 * kq + 2) * 2048 + col];
    float w3 = wT[(4 * kq + 3) * 2048 + col];
#pragma unroll
    for (int r = 0; r < 32; r++) {
      float4 x4 = xs4[r * 64 + kq];             // uniform address -> broadcast
      acc[r] += w0 * x4.x + w1 * x4.y + w2 * x4.z + w3 * x4.w;
    }
  }
  float bb = bias2[col];
  for (int r = 0; r < 32; r++)
    zpre[((size_t)d * T + (t0 + r)) * 1024 + g] = acc[r] + bb;
}

// ---------------------------------------------------------------------------
// K2 v3: sequential BiLSTM recurrence with LDS-RESIDENT f16 weights.
// 32 WGs (= d*16+sub), 256 thr. WG owns 16 cells -> 64 gate rows x 256 k.
// Weights live in 32 KB LDS (f16), laid out so each thread's per-step reads
// are ds_read_b128 at lane-contiguous addresses (conflict-free). Dot uses
// v_dot2_f32_f16. No register-residency gamble (rounds 1-3: allocator spilled
// any >=64-VGPR pinned array; streamed 256KB/step from L2 = 4100 cyc wall).
// Cross-WG h exchange: tagged {step,h} 8B atomics at AGENT scope, 2-slot ring.
// ---------------------------------------------------------------------------
__global__ __launch_bounds__(256) void k2_lstm(
    const float* __restrict__ zpre,
    const float* __restrict__ whf, const float* __restrict__ whb,
    const float* __restrict__ h0, const float* __restrict__ c0,
    float* h_all, unsigned long long* ring) {
  int w = blockIdx.x;
  int d = w >> 4, sub = w & 15;
  const float* w_hh = d ? whb : whf;
  int tid = threadIdx.x;

  __shared__ uint4 wl4[8 * 256];                 // 32 KB f16 weights
  __shared__ __align__(16) unsigned hpk[128];    // packed f16 h pairs
  __shared__ float z_lds[64];

  // ---- stage weights (once): k = q*64 + m*8 + j for thread (r,q) ----
  {
    unsigned short* wlh = (unsigned short*)wl4;
    for (int idx = tid; idx < 64 * 256; idx += 256) {
      int sr = idx >> 8, sk = idx & 255;
      int sgate = sr >> 4, scl = sr & 15;
      int grow = sgate * 256 + sub * 16 + scl;
      float wv = w_hh[(size_t)grow * 256 + sk];
      int sq = sk >> 6, rem = sk & 63, sm = rem >> 3, sj = rem & 7;
      wlh[((sm * 256) + (sr * 4 + sq)) * 8 + sj] = f16b(wv);
    }
  }

  float c = 0.f;
  if (tid < 16) c = c0[d * 256 + sub * 16 + tid];

  const float* zp_d = zpre + (size_t)d * T * 1024;
  float* h_d = h_all + (size_t)d * T * 256;
  unsigned long long* rg = ring + (size_t)d * 2 * 256;

  int r = tid >> 2, q = tid & 3;                 // 4 threads per gate row
  int gate = r >> 4, cl = r & 15;
  size_t zoff = (size_t)gate * 256 + sub * 16 + cl;   // q==0's z element

  int chunk = tid >> 4;                          // h index = tid
  bool is_poll = (chunk != sub);

  // init hpk from h0
  if (tid < 128) {
    unsigned pa = (unsigned)f16b(h0[d * 256 + 2 * tid]);
    unsigned pb = (unsigned)f16b(h0[d * 256 + 2 * tid + 1]);
    hpk[tid] = pa | (pb << 16);
  }

  float zv = 0.f;
  if (q == 0) zv = zp_d[(size_t)(d ? (T - 1) : 0) * 1024 + zoff];
  __syncthreads();                               // staging + hpk init done

  unsigned short* hpk_h = (unsigned short*)hpk;
  const uint4* hq = (const uint4*)hpk;           // hq[q*8+m]

  for (int s = 0; s < T; s++) {
    int t = d ? (T - 1 - s) : s;
    // prefetch next z before the poll -> HBM latency hidden under spin
    float zv_next = 0.f;
    if (q == 0 && s + 1 < T) {
      int tn = d ? (t - 1) : (t + 1);
      zv_next = zp_d[(size_t)tn * 1024 + zoff];
    }

    if (s > 0) {
      if (is_poll) {
        unsigned exp_tag = (unsigned)(s - 1);
        unsigned long long* addr = &rg[((s - 1) & 1) * 256 + tid];
        unsigned long long v;
        do {
          v = __hip_atomic_load(addr, __ATOMIC_RELAXED, __HIP_MEMORY_SCOPE_AGENT);
        } while ((unsigned)(v >> 32) != exp_tag);
        union { unsigned u; float f; } cv; cv.u = (unsigned)v;
        hpk_h[tid] = f16b(cv.f);
      }
      __syncthreads();                           // A: hpk complete
    }

    float acc = 0.f;
#pragma unroll
    for (int m = 0; m < 8; m++) {
      uint4 wv4 = wl4[m * 256 + tid];            // lane-contiguous: conflict-free
      uint4 hv4 = hq[q * 8 + m];                 // 4 addrs/wave: broadcast
      acc = dot2acc(wv4.x, hv4.x, acc);
      acc = dot2acc(wv4.y, hv4.y, acc);
      acc = dot2acc(wv4.z, hv4.z, acc);
      acc = dot2acc(wv4.w, hv4.w, acc);
    }
    acc += __shfl_xor(acc, 1);
    acc += __shfl_xor(acc, 2);
    if (q == 0) {
      float z = acc + zv;
      z_lds[r] = (gate == 2) ? tanh_fast(z) : sigm_fast(z);
    }
    __syncthreads();                             // B: activations complete

    if (tid < 16) {
      float iA = z_lds[tid], fA = z_lds[16 + tid];
      float gA = z_lds[32 + tid], oA = z_lds[48 + tid];
      c = fA * c + iA * gA;
      float hv = oA * tanh_fast(c);
      union { float f; unsigned u; } cv; cv.f = hv;
      // tagged push to MALL for the other 15 WGs of this direction
      __hip_atomic_store(&rg[(s & 1) * 256 + sub * 16 + tid],
                         ((unsigned long long)(unsigned)s << 32) | cv.u,
                         __ATOMIC_RELAXED, __HIP_MEMORY_SCOPE_AGENT);
      hpk_h[sub * 16 + tid] = f16b(hv);          // local chunk for next step
      h_d[(size_t)t * 256 + sub * 16 + tid] = hv;  // fp32 history for k3
    }
    zv = zv_next;
  }
}

// ---------------------------------------------------------------------------
// K3: feats[t][tag] = [hf[t]; hb[t]] . W_out[tag] + b_out[tag]
// ---------------------------------------------------------------------------
__global__ __launch_bounds__(64) void k3_feats(
    const float* __restrict__ h_all, const float* __restrict__ Wout,
    const float* __restrict__ bout, float* __restrict__ feats) {
  int t = blockIdx.x;
  int j = threadIdx.x;
  const float* hf = h_all + (size_t)t * 256;
  const float* hb = h_all + (size_t)T * 256 + (size_t)t * 256;
  float s[6];
#pragma unroll
  for (int g = 0; g < 6; g++) s[g] = 0.f;
#pragma unroll
  for (int m = 0; m < 4; m++) {
    float a = hf[j + 64 * m];
#pragma unroll
    for (int g = 0; g < 6; g++) s[g] += a * Wout[g * 512 + j + 64 * m];
  }
#pragma unroll
  for (int m = 0; m < 4; m++) {
    float b = hb[j + 64 * m];
#pragma unroll
    for (int g = 0; g < 6; g++) s[g] += b * Wout[g * 512 + 256 + j + 64 * m];
  }
#pragma unroll
  for (int g = 0; g < 6; g++) {
#pragma unroll
    for (int off = 32; off >= 1; off >>= 1) s[g] += __shfl_xor(s[g], off);
  }
  if (j < 6) feats[(size_t)t * 6 + j] = s[j] + bout[j];
}

// ---------------------------------------------------------------------------
// K4: Viterbi forward (serial, first-max argmax like jnp.argmax) + parallel
// backtrace via 6-entry map-composition suffix scan. Single wave.
// ---------------------------------------------------------------------------
__global__ __launch_bounds__(64) void k4_viterbi(
    const float* __restrict__ feats, const float* __restrict__ trans,
    float* __restrict__ out) {
  __shared__ unsigned char bp_lds[T * 8];
  __shared__ float fbuf[2][64 * 6];
  int lane = threadIdx.x;

  float tr[6];
#pragma unroll
  for (int f = 0; f < 6; f++) tr[f] = (lane < 6) ? trans[lane * 6 + f] : 0.f;
  float fv = (lane == START_TAG) ? 0.f : NEGV;

  for (int idx = lane; idx < 384; idx += 64) fbuf[0][idx] = feats[idx];

  for (int cch = 0; cch < 64; cch++) {
    float pf[6];
    if (cch + 1 < 64) {
#pragma unroll
      for (int m = 0; m < 6; m++)
        pf[m] = feats[(cch + 1) * 384 + lane + 64 * m];   // prefetch in regs
    }
    const float* fb = fbuf[cch & 1];
    for (int j = 0; j < 64; j++) {
      int t = cch * 64 + j;
      float best = -3.4e38f;
      int bi = 0;
#pragma unroll
      for (int f = 0; f < 6; f++) {
        float v = __shfl(fv, f) + tr[f];     // trans[to][from] + fv[from]
        if (v > best) { best = v; bi = f; }  // strict > => first max index
      }
      float nfv = best + fb[j * 6 + (lane < 6 ? lane : 0)];
      if (lane < 6) {
        fv = nfv;
        bp_lds[t * 8 + lane] = (unsigned char)bi;
      }
    }
    if (cch + 1 < 64) {
#pragma unroll
      for (int m = 0; m < 6; m++)
        fbuf[(cch + 1) & 1][lane + 64 * m] = pf[m];
    }
  }

  float term = (lane < 6) ? (fv + trans[STOP_TAG * 6 + lane]) : -3.4e38f;
  float bestv = -3.4e38f;
  int bestt = 0;
#pragma unroll
  for (int f = 0; f < 6; f++) {
    float v = __shfl(term, f);
    if (v > bestv) { bestv = v; bestt = f; }
  }
  if (lane == 0) out[0] = bestv;

  // backtrace: path[t] = S_t(best), S_t = M_{t+1} o ... o M_{T-1}
  unsigned int ident = 0;
#pragma unroll
  for (int i = 0; i < 6; i++) ident |= (unsigned)i << (3 * i);

  unsigned int p = ident;                 // P_L = M_{64L} o ... o M_{64L+63}
  int base = lane * 64;
  for (int j2 = 0; j2 < 64; j2++) {
    const unsigned int* bw = (const unsigned int*)&bp_lds[(base + j2) * 8];
    unsigned int lo = bw[0], hi = bw[1];
    unsigned int mw = (lo & 7) | (((lo >> 8) & 7) << 3) | (((lo >> 16) & 7) << 6)
                    | (((lo >> 24) & 7) << 9) | ((hi & 7) << 12)
                    | (((hi >> 8) & 7) << 15);
    unsigned int np = 0;
#pragma unroll
    for (int i = 0; i < 6; i++) {
      unsigned int b = (mw >> (3 * i)) & 7;
      np |= ((p >> (3 * b)) & 7) << (3 * i);   // p := p o M_t
    }
    p = np;
  }
  unsigned int suf = p;   // suffix scan: suf_L = P_L o ... o P_63
#pragma unroll
  for (int off = 1; off < 64; off <<= 1) {
    unsigned int other = __shfl_down(suf, off);
    if (lane + off < 64) {
      unsigned int ns = 0;
#pragma unroll
      for (int i = 0; i < 6; i++) {
        unsigned int b = (other >> (3 * i)) & 7;
        ns |= ((suf >> (3 * b)) & 7) << (3 * i);   // suf := suf o other
      }
      suf = ns;
    }
  }
  unsigned int tail = __shfl_down(suf, 1);     // Suf_{L+1}
  if (lane == 63) tail = ident;
  unsigned int cur = tail;                     // = S_{64L+63}
  for (int j2 = 63; j2 >= 0; j2--) {
    int t = base + j2;
    out[1 + t] = (float)((cur >> (3 * bestt)) & 7);
    const unsigned int* bw = (const unsigned int*)&bp_lds[t * 8];
    unsigned int lo = bw[0], hi = bw[1];
    unsigned int mw = (lo & 7) | (((lo >> 8) & 7) << 3) | (((lo >> 16) & 7) << 6)
                    | (((lo >> 24) & 7) << 9) | ((hi & 7) << 12)
                    | (((hi >> 8) & 7) << 15);
    unsigned int nc = 0;
#pragma unroll
    for (int i = 0; i < 6; i++) {
      unsigned int b = (cur >> (3 * i)) & 7;
      nc |= ((mw >> (3 * b)) & 7) << (3 * i);  // cur := M_t o cur
    }
    cur = nc;
  }
}

// ---------------------------------------------------------------------------
extern "C" void kernel_launch(void* const* d_in, const int* in_sizes, int n_in,
                              void* d_out, int out_size, void* d_ws, size_t ws_size,
                              hipStream_t stream) {
  const int*   sent  = (const int*)d_in[0];
  const float* emb   = (const float*)d_in[1];
  const float* wihf  = (const float*)d_in[2];
  const float* whhf  = (const float*)d_in[3];
  const float* bihf  = (const float*)d_in[4];
  const float* bhhf  = (const float*)d_in[5];
  const float* wihb  = (const float*)d_in[6];
  const float* whhb  = (const float*)d_in[7];
  const float* bihb  = (const float*)d_in[8];
  const float* bhhb  = (const float*)d_in[9];
  const float* Wout  = (const float*)d_in[10];
  const float* bout  = (const float*)d_in[11];
  const float* trans = (const float*)d_in[12];
  const float* h0    = (const float*)d_in[13];
  const float* c0    = (const float*)d_in[14];
  float* out = (float*)d_out;

  char* ws = (char*)d_ws;
  float*              zpre  = (float*)(ws + 0);          // 32 MiB
  float*              h_all = (float*)(ws + 33554432);   //  8 MiB
  float*              wT    = (float*)(ws + 41943040);   //  2 MiB
  float*              bias2 = (float*)(ws + 44040192);   //  8 KiB
  float*              feats = (float*)(ws + 44048384);   // 96 KiB
  unsigned long long* ring  = (unsigned long long*)(ws + 44146688); // 8 KiB

  k0_prep<<<2048, 256, 0, stream>>>(wihf, wihb, bihf, bhhf, bihb, bhhb, wT, bias2);
  dim3 g1(128, 8);
  k1_zpre<<<g1, 256, 0, stream>>>(sent, emb, wT, bias2, zpre);
  k2_lstm<<<32, 256, 0, stream>>>(zpre, whhf, whhb, h0, c0, h_all, ring);
  k3_feats<<<4096, 64, 0, stream>>>(h_all, Wout, bout, feats);
  k4_viterbi<<<1, 64, 0, stream>>>(feats, trans, out);
}

// Round 5
// 6478.094 us; speedup vs baseline: 1.5045x; 1.0370x over previous
//
#include <hip/hip_runtime.h>
#include <stdint.h>
#include <math.h>

#define T 4096
#define NTAGS 6
#define START_TAG 3
#define STOP_TAG 4
#define NEGV -10000.0f

__device__ __forceinline__ float sigm_fast(float z) {
  return 1.f / (1.f + __expf(-z));
}
__device__ __forceinline__ float tanh_fast(float z) {
  return 1.f - 2.f / (1.f + __expf(2.f * z));   // exact at +/-inf saturation
}

typedef _Float16 half2v __attribute__((ext_vector_type(2)));
__device__ __forceinline__ float dot2acc(unsigned a, unsigned b, float c) {
  return __builtin_amdgcn_fdot2(__builtin_bit_cast(half2v, a),
                                __builtin_bit_cast(half2v, b), c, false);
}
__device__ __forceinline__ unsigned short f16b(float x) {
  _Float16 h = (_Float16)x;
  return __builtin_bit_cast(unsigned short, h);
}

// ---------------------------------------------------------------------------
// K0: transpose w_ih (both dirs) into wT[k][col], col = d*1024+g; combined bias
// ---------------------------------------------------------------------------
__global__ __launch_bounds__(256) void k0_prep(
    const float* __restrict__ wf, const float* __restrict__ wb,
    const float* __restrict__ bif, const float* __restrict__ bhf,
    const float* __restrict__ bib, const float* __restrict__ bhb,
    float* __restrict__ wT, float* __restrict__ bias2) {
  int idx = blockIdx.x * 256 + threadIdx.x;   // 0 .. 524287
  int k = idx >> 11, col = idx & 2047;
  int d = col >> 10, g = col & 1023;
  const float* w = d ? wb : wf;
  wT[idx] = w[g * 256 + k];                   // wT[k*2048 + col]
  if (idx < 2048) bias2[idx] = d ? (bib[g] + bhb[g]) : (bif[g] + bhf[g]);
}

// ---------------------------------------------------------------------------
// K1: zpre[d][t][g] = emb[sent[t]] . w_ih[d][g] + b_ih + b_hh
// ---------------------------------------------------------------------------
__global__ __launch_bounds__(256) void k1_zpre(
    const int* __restrict__ sent, const float* __restrict__ emb,
    const float* __restrict__ wT, const float* __restrict__ bias2,
    float* __restrict__ zpre) {
  int tb = blockIdx.x, cb = blockIdx.y;
  int tid = threadIdx.x;
  int col = cb * 256 + tid;
  int d = col >> 10, g = col & 1023;
  __shared__ float xs[32 * 256];
  int t0 = tb * 32;
  for (int r = 0; r < 32; r++) {
    int s = sent[t0 + r];                       // uniform -> scalar broadcast
    xs[r * 256 + tid] = emb[(size_t)s * 256 + tid];
  }
  __syncthreads();
  float acc[32];
#pragma unroll
  for (int r = 0; r < 32; r++) acc[r] = 0.f;
  const float4* xs4 = (const float4*)xs;
  for (int kq = 0; kq < 64; kq++) {
    float w0 = wT[(4 * kq + 0) * 2048 + col];
    float w1 = wT[(4 * kq + 1) * 2048 + col];
    float w2 = wT[(4 * kq + 2) * 2048 + col];
    float w3 = wT[(4 * kq + 3) * 2048 + col];
#pragma unroll
    for (int r = 0; r < 32; r++) {
      float4 x4 = xs4[r * 64 + kq];             // uniform address -> broadcast
      acc[r] += w0 * x4.x + w1 * x4.y + w2 * x4.z + w3 * x4.w;
    }
  }
  float bb = bias2[col];
  for (int r = 0; r < 32; r++)
    zpre[((size_t)d * T + (t0 + r)) * 1024 + g] = acc[r] + bb;
}

// ---------------------------------------------------------------------------
// K2 v4: LDS-resident f16 weights, k-SPLIT ACROSS WAVES.
// 32 WGs (= d*16+sub), 256 thr. WG owns 16 cells -> 64 gate rows.
// Wave q covers k in [64q,64q+64) for ALL 64 rows; it polls its own
// wave-private 32-entry h slice from the packed ring (2 f16/entry, tagged)
// -> NO cross-wave barrier for h. Cross-wave z-reduction via z_part LDS.
// 2 barriers/step. Ring: AGENT-scope tagged 8B atomics (MALL-coherent).
// ---------------------------------------------------------------------------
__global__ __launch_bounds__(256) void k2_lstm(
    const float* __restrict__ zpre,
    const float* __restrict__ whf, const float* __restrict__ whb,
    const float* __restrict__ h0, const float* __restrict__ c0,
    float* h_all, unsigned long long* ring) {
  int w = blockIdx.x;
  int d = w >> 4, sub = w & 15;
  const float* w_hh = d ? whb : whf;
  int tid = threadIdx.x;
  int q = tid >> 6, lane = tid & 63;

  __shared__ uint4 wl4[32 * 64];                    // 32 KB f16 weights
  __shared__ __align__(16) unsigned hq[4][32];      // per-wave h2 slices
  __shared__ float z_part[4][64];                   // per-wave partial z

  // ---- stage weights once: half index ((q*8+m)*64 + r)*8 + j, k=64q+8m+j ---
  {
    unsigned short* wlh = (unsigned short*)wl4;
    for (int idx = tid; idx < 64 * 256; idx += 256) {
      int r = idx >> 8, k = idx & 255;
      int gate = r >> 4, cell = r & 15;
      float wv = w_hh[(size_t)(gate * 256 + sub * 16 + cell) * 256 + k];
      int sq = k >> 6, sm = (k >> 3) & 7, sj = k & 7;
      wlh[((sq * 8 + sm) * 64 + r) * 8 + sj] = f16b(wv);
    }
  }
  // ---- h0 into wave slices ----
  if (lane < 32) {
    float f0 = h0[d * 256 + q * 64 + 2 * lane];
    float f1 = h0[d * 256 + q * 64 + 2 * lane + 1];
    hq[q][lane] = (unsigned)f16b(f0) | ((unsigned)f16b(f1) << 16);
  }
  float c = 0.f;
  if (tid < 16) c = c0[d * 256 + sub * 16 + tid];

  const float* zp_d = zpre + (size_t)d * T * 1024;
  float* h_d = h_all + (size_t)d * T * 256;
  unsigned long long* rg = ring + (size_t)d * 2 * 128;

  // zpre for s=0, held by the 16 updater threads (4 gates each)
  float zv4[4] = {0.f, 0.f, 0.f, 0.f};
  if (tid < 16) {
    int t0 = d ? (T - 1) : 0;
#pragma unroll
    for (int g = 0; g < 4; g++)
      zv4[g] = zp_d[(size_t)t0 * 1024 + g * 256 + sub * 16 + tid];
  }
  __syncthreads();                                  // staging + h0 visible

  for (int s = 0; s < T; s++) {
    int t = d ? (T - 1 - s) : s;
    // prefetch next-step zpre BEFORE the poll: HBM latency hides under spin
    float zn4[4] = {0.f, 0.f, 0.f, 0.f};
    if (tid < 16 && s + 1 < T) {
      int tn = d ? (t - 1) : (t + 1);
#pragma unroll
      for (int g = 0; g < 4; g++)
        zn4[g] = zp_d[(size_t)tn * 1024 + g * 256 + sub * 16 + tid];
    }

    if (s > 0 && lane < 32) {
      unsigned exp_tag = (unsigned)s;               // tag of step s-1 is s
      unsigned long long* addr = &rg[((s - 1) & 1) * 128 + q * 32 + lane];
      unsigned long long v;
      do {
        v = __hip_atomic_load(addr, __ATOMIC_RELAXED, __HIP_MEMORY_SCOPE_AGENT);
      } while ((unsigned)(v >> 32) != exp_tag);
      hq[q][lane] = (unsigned)v;                    // wave-private slice
    }
    __builtin_amdgcn_wave_barrier();                // order hq write vs reads

    const uint4* hv = (const uint4*)hq[q];
    float acc = 0.f;
#pragma unroll
    for (int m = 0; m < 8; m++) {
      uint4 wv4 = wl4[(q * 8 + m) * 64 + lane];     // contiguous b128
      uint4 hv4 = hv[m];                            // wave-uniform broadcast
      acc = dot2acc(wv4.x, hv4.x, acc);
      acc = dot2acc(wv4.y, hv4.y, acc);
      acc = dot2acc(wv4.z, hv4.z, acc);
      acc = dot2acc(wv4.w, hv4.w, acc);
    }
    z_part[q][lane] = acc;
    __syncthreads();                                // (1) partials ready

    if (tid < 16) {
      float a[4];
#pragma unroll
      for (int g = 0; g < 4; g++) {
        int r = g * 16 + tid;
        float z = z_part[0][r] + z_part[1][r] + z_part[2][r] + z_part[3][r]
                + zv4[g];
        a[g] = (g == 2) ? tanh_fast(z) : sigm_fast(z);
      }
      c = a[1] * c + a[0] * a[2];
      float hvl = a[3] * tanh_fast(c);
      h_d[(size_t)t * 256 + sub * 16 + tid] = hvl;  // fp32 history for k3
      float hn = __shfl_down(hvl, 1);
      if ((tid & 1) == 0) {                         // pack 2 h per tagged entry
        unsigned h2 = (unsigned)f16b(hvl) | ((unsigned)f16b(hn) << 16);
        __hip_atomic_store(&rg[(s & 1) * 128 + sub * 8 + (tid >> 1)],
                           ((unsigned long long)(unsigned)(s + 1) << 32) | h2,
                           __ATOMIC_RELAXED, __HIP_MEMORY_SCOPE_AGENT);
      }
#pragma unroll
      for (int g = 0; g < 4; g++) zv4[g] = zn4[g];
    }
    __syncthreads();                                // (2) z_part safe to reuse
  }
}

// ---------------------------------------------------------------------------
// K3: feats[t][tag] = [hf[t]; hb[t]] . W_out[tag] + b_out[tag]
// ---------------------------------------------------------------------------
__global__ __launch_bounds__(64) void k3_feats(
    const float* __restrict__ h_all, const float* __restrict__ Wout,
    const float* __restrict__ bout, float* __restrict__ feats) {
  int t = blockIdx.x;
  int j = threadIdx.x;
  const float* hf = h_all + (size_t)t * 256;
  const float* hb = h_all + (size_t)T * 256 + (size_t)t * 256;
  float s[6];
#pragma unroll
  for (int g = 0; g < 6; g++) s[g] = 0.f;
#pragma unroll
  for (int m = 0; m < 4; m++) {
    float a = hf[j + 64 * m];
#pragma unroll
    for (int g = 0; g < 6; g++) s[g] += a * Wout[g * 512 + j + 64 * m];
  }
#pragma unroll
  for (int m = 0; m < 4; m++) {
    float b = hb[j + 64 * m];
#pragma unroll
    for (int g = 0; g < 6; g++) s[g] += b * Wout[g * 512 + 256 + j + 64 * m];
  }
#pragma unroll
  for (int g = 0; g < 6; g++) {
#pragma unroll
    for (int off = 32; off >= 1; off >>= 1) s[g] += __shfl_xor(s[g], off);
  }
  if (j < 6) feats[(size_t)t * 6 + j] = s[j] + bout[j];
}

// ---------------------------------------------------------------------------
// K4: Viterbi forward (serial, first-max argmax like jnp.argmax) + parallel
// backtrace via 6-entry map-composition suffix scan. Single wave.
// ---------------------------------------------------------------------------
__global__ __launch_bounds__(64) void k4_viterbi(
    const float* __restrict__ feats, const float* __restrict__ trans,
    float* __restrict__ out) {
  __shared__ unsigned char bp_lds[T * 8];
  __shared__ float fbuf[2][64 * 6];
  int lane = threadIdx.x;

  float tr[6];
#pragma unroll
  for (int f = 0; f < 6; f++) tr[f] = (lane < 6) ? trans[lane * 6 + f] : 0.f;
  float fv = (lane == START_TAG) ? 0.f : NEGV;

  for (int idx = lane; idx < 384; idx += 64) fbuf[0][idx] = feats[idx];

  for (int cch = 0; cch < 64; cch++) {
    float pf[6];
    if (cch + 1 < 64) {
#pragma unroll
      for (int m = 0; m < 6; m++)
        pf[m] = feats[(cch + 1) * 384 + lane + 64 * m];   // prefetch in regs
    }
    const float* fb = fbuf[cch & 1];
    for (int j = 0; j < 64; j++) {
      int t = cch * 64 + j;
      float best = -3.4e38f;
      int bi = 0;
#pragma unroll
      for (int f = 0; f < 6; f++) {
        float v = __shfl(fv, f) + tr[f];     // trans[to][from] + fv[from]
        if (v > best) { best = v; bi = f; }  // strict > => first max index
      }
      float nfv = best + fb[j * 6 + (lane < 6 ? lane : 0)];
      if (lane < 6) {
        fv = nfv;
        bp_lds[t * 8 + lane] = (unsigned char)bi;
      }
    }
    if (cch + 1 < 64) {
#pragma unroll
      for (int m = 0; m < 6; m++)
        fbuf[(cch + 1) & 1][lane + 64 * m] = pf[m];
    }
  }

  float term = (lane < 6) ? (fv + trans[STOP_TAG * 6 + lane]) : -3.4e38f;
  float bestv = -3.4e38f;
  int bestt = 0;
#pragma unroll
  for (int f = 0; f < 6; f++) {
    float v = __shfl(term, f);
    if (v > bestv) { bestv = v; bestt = f; }
  }
  if (lane == 0) out[0] = bestv;

  // backtrace: path[t] = S_t(best), S_t = M_{t+1} o ... o M_{T-1}
  unsigned int ident = 0;
#pragma unroll
  for (int i = 0; i < 6; i++) ident |= (unsigned)i << (3 * i);

  unsigned int p = ident;                 // P_L = M_{64L} o ... o M_{64L+63}
  int base = lane * 64;
  for (int j2 = 0; j2 < 64; j2++) {
    const unsigned int* bw = (const unsigned int*)&bp_lds[(base + j2) * 8];
    unsigned int lo = bw[0], hi = bw[1];
    unsigned int mw = (lo & 7) | (((lo >> 8) & 7) << 3) | (((lo >> 16) & 7) << 6)
                    | (((lo >> 24) & 7) << 9) | ((hi & 7) << 12)
                    | (((hi >> 8) & 7) << 15);
    unsigned int np = 0;
#pragma unroll
    for (int i = 0; i < 6; i++) {
      unsigned int b = (mw >> (3 * i)) & 7;
      np |= ((p >> (3 * b)) & 7) << (3 * i);   // p := p o M_t
    }
    p = np;
  }
  unsigned int suf = p;   // suffix scan: suf_L = P_L o ... o P_63
#pragma unroll
  for (int off = 1; off < 64; off <<= 1) {
    unsigned int other = __shfl_down(suf, off);
    if (lane + off < 64) {
      unsigned int ns = 0;
#pragma unroll
      for (int i = 0; i < 6; i++) {
        unsigned int b = (other >> (3 * i)) & 7;
        ns |= ((suf >> (3 * b)) & 7) << (3 * i);   // suf := suf o other
      }
      suf = ns;
    }
  }
  unsigned int tail = __shfl_down(suf, 1);     // Suf_{L+1}
  if (lane == 63) tail = ident;
  unsigned int cur = tail;                     // = S_{64L+63}
  for (int j2 = 63; j2 >= 0; j2--) {
    int t = base + j2;
    out[1 + t] = (float)((cur >> (3 * bestt)) & 7);
    const unsigned int* bw = (const unsigned int*)&bp_lds[t * 8];
    unsigned int lo = bw[0], hi = bw[1];
    unsigned int mw = (lo & 7) | (((lo >> 8) & 7) << 3) | (((lo >> 16) & 7) << 6)
                    | (((lo >> 24) & 7) << 9) | ((hi & 7) << 12)
                    | (((hi >> 8) & 7) << 15);
    unsigned int nc = 0;
#pragma unroll
    for (int i = 0; i < 6; i++) {
      unsigned int b = (cur >> (3 * i)) & 7;
      nc |= ((mw >> (3 * b)) & 7) << (3 * i);  // cur := M_t o cur
    }
    cur = nc;
  }
}

// ---------------------------------------------------------------------------
extern "C" void kernel_launch(void* const* d_in, const int* in_sizes, int n_in,
                              void* d_out, int out_size, void* d_ws, size_t ws_size,
                              hipStream_t stream) {
  const int*   sent  = (const int*)d_in[0];
  const float* emb   = (const float*)d_in[1];
  const float* wihf  = (const float*)d_in[2];
  const float* whhf  = (const float*)d_in[3];
  const float* bihf  = (const float*)d_in[4];
  const float* bhhf  = (const float*)d_in[5];
  const float* wihb  = (const float*)d_in[6];
  const float* whhb  = (const float*)d_in[7];
  const float* bihb  = (const float*)d_in[8];
  const float* bhhb  = (const float*)d_in[9];
  const float* Wout  = (const float*)d_in[10];
  const float* bout  = (const float*)d_in[11];
  const float* trans = (const float*)d_in[12];
  const float* h0    = (const float*)d_in[13];
  const float* c0    = (const float*)d_in[14];
  float* out = (float*)d_out;

  char* ws = (char*)d_ws;
  float*              zpre  = (float*)(ws + 0);          // 32 MiB
  float*              h_all = (float*)(ws + 33554432);   //  8 MiB
  float*              wT    = (float*)(ws + 41943040);   //  2 MiB
  float*              bias2 = (float*)(ws + 44040192);   //  8 KiB
  float*              feats = (float*)(ws + 44048384);   // 96 KiB
  unsigned long long* ring  = (unsigned long long*)(ws + 44146688); // 4 KiB

  k0_prep<<<2048, 256, 0, stream>>>(wihf, wihb, bihf, bhhf, bihb, bhhb, wT, bias2);
  dim3 g1(128, 8);
  k1_zpre<<<g1, 256, 0, stream>>>(sent, emb, wT, bias2, zpre);
  k2_lstm<<<32, 256, 0, stream>>>(zpre, whhf, whhb, h0, c0, h_all, ring);
  k3_feats<<<4096, 64, 0, stream>>>(h_all, Wout, bout, feats);
  k4_viterbi<<<1, 64, 0, stream>>>(feats, trans, out);
}